// Round 3
// baseline (5445.680 us; speedup 1.0000x reference)
//
#include <hip/hip_runtime.h>

#define Cn 16
#define Bn 128
#define Hn 40
#define Wn 40
#define Sn 32
#define HID 128
#define PIX (Bn * Hn * Wn)          // 204800
#define NFRAME (Sn + 1)             // 33
#define RGB_TOTAL (NFRAME * PIX * 3)
#define STACK_FRAME (PIX * Cn)
#define ALPHA_T 0.1f
#define NCHUNK (PIX / 256)          // 800 chunks of 256 pixels per frame

// ===========================================================================
// Compaction precompute (runs once): ordered per-step lists of active pixels.
// upd_mask is a static input, so all 32 lists are built up front.
// ===========================================================================

// counts[t*NCHUNK + c] = number of active pixels in chunk c of step t
__global__ __launch_bounds__(256) void mask_count(
    const int* __restrict__ upd, int* __restrict__ counts)
{
    int i = blockIdx.x * 256 + threadIdx.x;       // global into upd [Sn*PIX]
    bool m = upd[i] != 0;
    unsigned long long b = __ballot(m);
    __shared__ int wc[4];
    int lane = threadIdx.x & 63, w = threadIdx.x >> 6;
    if (lane == 0) wc[w] = __popcll(b);
    __syncthreads();
    if (threadIdx.x == 0) counts[blockIdx.x] = wc[0] + wc[1] + wc[2] + wc[3];
}

// Per-step exclusive scan of chunk counts; nAct[t] = total active in step t.
__global__ __launch_bounds__(1024) void scan_counts(
    const int* __restrict__ counts, int* __restrict__ base, int* __restrict__ nAct)
{
    int t = blockIdx.x;                            // one block per step
    __shared__ int bufA[NCHUNK];
    __shared__ int bufB[NCHUNK];
    for (int c = threadIdx.x; c < NCHUNK; c += 1024) bufA[c] = counts[t * NCHUNK + c];
    __syncthreads();
    int* src = bufA; int* dst = bufB;
    for (int off = 1; off < NCHUNK; off <<= 1) {
        for (int c = threadIdx.x; c < NCHUNK; c += 1024)
            dst[c] = src[c] + ((c >= off) ? src[c - off] : 0);
        __syncthreads();
        int* tmp = src; src = dst; dst = tmp;
    }
    // src = inclusive scan
    for (int c = threadIdx.x; c < NCHUNK; c += 1024)
        base[t * NCHUNK + c] = (c == 0) ? 0 : src[c - 1];
    if (threadIdx.x == 0) nAct[t] = src[NCHUNK - 1];
}

// list[t*PIX + base + rank] = pixel index (ascending within each step)
__global__ __launch_bounds__(256) void mask_fill(
    const int* __restrict__ upd, const int* __restrict__ base, int* __restrict__ list)
{
    int blk = blockIdx.x;                          // t*NCHUNK + c
    int t   = blk / NCHUNK;
    int i   = blk * 256 + threadIdx.x;             // global into upd
    int pix = i - t * PIX;                         // pixel index within frame
    bool m = upd[i] != 0;
    unsigned long long b = __ballot(m);
    int lane = threadIdx.x & 63, w = threadIdx.x >> 6;
    int rank = __popcll(b & (((unsigned long long)1 << lane) - 1ull));
    __shared__ int wcnt[4], wexc[4];
    if (lane == 0) wcnt[w] = __popcll(b);
    __syncthreads();
    if (threadIdx.x == 0) {
        int s = 0;
        for (int k = 0; k < 4; ++k) { wexc[k] = s; s += wcnt[k]; }
    }
    __syncthreads();
    if (m) list[t * PIX + base[blk] + wexc[w] + rank] = pix;
}

// ===========================================================================
// Kernel A (compact): block = 256 threads = 128 pixels x 2 hidden-halves.
//   P[idx] = S[idx] + (W2 @ relu(W1 @ perception + b1))   for active pixels
// Also overwrites PaM[idx] (pre-mask alpha plane) at active pixels; inactive
// entries keep the prefill = alpha(S) written by the previous step_mask.
// Weights stay wave-uniform (scalar pipe); each wave streams only its half
// (16.5 KB, fits the scalar cache).
// ===========================================================================
__global__ __launch_bounds__(256) void step_update_c(
    const float* __restrict__ S,      // [PIX*16] current (masked) state
    const float* __restrict__ amF,    // [PIX] alive mask of S
    const int*   __restrict__ nActP,  // &nAct[t]
    const int*   __restrict__ list,   // active pixel indices for this step
    float*       __restrict__ P,      // [PIX*16] out: pre-mask new state
    float*       __restrict__ PaM,    // [PIX] pre-mask alpha plane (partial write)
    const float* __restrict__ W1,     // [128*48]
    const float* __restrict__ b1,     // [128]
    const float* __restrict__ W2T)    // [128*16]
{
    __shared__ float redUpd[128][16];

    int nAct  = *nActP;
    int p     = threadIdx.x & 127;
    int halfI = threadIdx.x >> 7;                 // 0: waves 0-1, 1: waves 2-3 (wave-uniform)
    int i     = blockIdx.x * 128 + p;
    bool act  = i < nAct;

    int idx = 0;
    float upd[16];
    float4 cen[4];

    if (act) {
        idx = list[i];
        int x  = idx % Wn;
        int t1 = idx / Wn;
        int y  = t1 % Hn;

        // alive mask of 3x3 neighborhood from precomputed field
        float am[3][3];
#pragma unroll
        for (int dy = 0; dy < 3; ++dy) {
#pragma unroll
            for (int dx = 0; dx < 3; ++dx) {
                int yy = y + dy - 1, xx = x + dx - 1;
                bool in = (yy >= 0) && (yy < Hn) && (xx >= 0) && (xx < Wn);
                am[dy][dx] = in ? amF[idx + (dy - 1) * Wn + (dx - 1)] : 0.f;
            }
        }

        // perception: [masked(16) | sobel_x(16) | sobel_y(16)]
        float perc[48];
#pragma unroll
        for (int cg = 0; cg < 4; ++cg) {
            float4 m[3][3];
#pragma unroll
            for (int dy = 0; dy < 3; ++dy) {
#pragma unroll
                for (int dx = 0; dx < 3; ++dx) {
                    int yy = y + dy - 1, xx = x + dx - 1;
                    bool in = (yy >= 0) && (yy < Hn) && (xx >= 0) && (xx < Wn);
                    float4 v;
                    if (in) {
                        v = *(const float4*)&S[(idx + (dy - 1) * Wn + (dx - 1)) * Cn + cg * 4];
                        if (dy == 1 && dx == 1) cen[cg] = v;
                        float a = am[dy][dx];
                        v.x *= a; v.y *= a; v.z *= a; v.w *= a;
                    } else {
                        v.x = 0.f; v.y = 0.f; v.z = 0.f; v.w = 0.f;
                    }
                    m[dy][dx] = v;
                }
            }
            perc[cg * 4 + 0] = m[1][1].x;
            perc[cg * 4 + 1] = m[1][1].y;
            perc[cg * 4 + 2] = m[1][1].z;
            perc[cg * 4 + 3] = m[1][1].w;
            perc[16 + cg * 4 + 0] = ((m[0][2].x - m[0][0].x) + 2.f * (m[1][2].x - m[1][0].x) + (m[2][2].x - m[2][0].x)) * 0.125f;
            perc[16 + cg * 4 + 1] = ((m[0][2].y - m[0][0].y) + 2.f * (m[1][2].y - m[1][0].y) + (m[2][2].y - m[2][0].y)) * 0.125f;
            perc[16 + cg * 4 + 2] = ((m[0][2].z - m[0][0].z) + 2.f * (m[1][2].z - m[1][0].z) + (m[2][2].z - m[2][0].z)) * 0.125f;
            perc[16 + cg * 4 + 3] = ((m[0][2].w - m[0][0].w) + 2.f * (m[1][2].w - m[1][0].w) + (m[2][2].w - m[2][0].w)) * 0.125f;
            perc[32 + cg * 4 + 0] = ((m[2][0].x - m[0][0].x) + 2.f * (m[2][1].x - m[0][1].x) + (m[2][2].x - m[0][2].x)) * 0.125f;
            perc[32 + cg * 4 + 1] = ((m[2][0].y - m[0][0].y) + 2.f * (m[2][1].y - m[0][1].y) + (m[2][2].y - m[0][2].y)) * 0.125f;
            perc[32 + cg * 4 + 2] = ((m[2][0].z - m[0][0].z) + 2.f * (m[2][1].z - m[0][1].z) + (m[2][2].z - m[0][2].z)) * 0.125f;
            perc[32 + cg * 4 + 3] = ((m[2][0].w - m[0][0].w) + 2.f * (m[2][1].w - m[0][1].w) + (m[2][2].w - m[0][2].w)) * 0.125f;
        }

        // MLP half: rows [halfI*64, halfI*64+64)
#pragma unroll
        for (int c = 0; c < 16; ++c) upd[c] = 0.f;

        const float* W1h = W1  + halfI * (64 * 48);
        const float* b1h = b1  + halfI * 64;
        const float* W2h = W2T + halfI * (64 * 16);

#pragma unroll 2
        for (int j = 0; j < 64; ++j) {
            const float* w = &W1h[j * 48];
            float hh0 = b1h[j], hh1 = 0.f, hh2 = 0.f, hh3 = 0.f;
#pragma unroll
            for (int q = 0; q < 12; ++q) {
                hh0 = fmaf(perc[q],      w[q],      hh0);
                hh1 = fmaf(perc[12 + q], w[12 + q], hh1);
                hh2 = fmaf(perc[24 + q], w[24 + q], hh2);
                hh3 = fmaf(perc[36 + q], w[36 + q], hh3);
            }
            float h = fmaxf((hh0 + hh1) + (hh2 + hh3), 0.f);
            const float* w2 = &W2h[j * 16];
#pragma unroll
            for (int c = 0; c < 16; ++c) upd[c] = fmaf(h, w2[c], upd[c]);
        }

        if (halfI == 1) {
#pragma unroll
            for (int cg = 0; cg < 4; ++cg)
                *(float4*)&redUpd[p][cg * 4] = *(float4*)&upd[cg * 4];
        }
    }

    __syncthreads();

    if (act && halfI == 0) {
#pragma unroll
        for (int cg = 0; cg < 4; ++cg) {
            float4 o = *(float4*)&redUpd[p][cg * 4];
            float4 s = cen[cg];
            o.x = s.x + (upd[cg * 4 + 0] + o.x);
            o.y = s.y + (upd[cg * 4 + 1] + o.y);
            o.z = s.z + (upd[cg * 4 + 2] + o.z);
            o.w = s.w + (upd[cg * 4 + 3] + o.w);
            *(float4*)&P[idx * Cn + cg * 4] = o;
            if (cg == 0) PaM[idx] = o.w;          // channel 3 = alpha
        }
    }
}

// ===========================================================================
// Kernel B (dense): premask state v = fm ? P : S; S_next = v * alive(v);
// writes amF (alive of S_next) and prefills PaM_next = alpha(S_next).
// Alpha gather comes from the merged pre-mask alpha plane PaM_cur.
// ===========================================================================
__global__ __launch_bounds__(256) void step_mask(
    const float* __restrict__ P,
    const float* __restrict__ PaCur,   // pre-mask alpha plane (merged)
    const float* __restrict__ S,       // current state (for fm==0 pixels)
    const int*   __restrict__ maskT,   // update mask this step
    float*       __restrict__ Snext,
    float*       __restrict__ amNext,
    float*       __restrict__ PaNxt)   // out: alpha(S_next) prefill
{
    int idx = blockIdx.x * 256 + threadIdx.x;
    int x  = idx % Wn;
    int t1 = idx / Wn;
    int y  = t1 % Hn;

    float a[5][5];
#pragma unroll
    for (int dy = 0; dy < 5; ++dy) {
#pragma unroll
        for (int dx = 0; dx < 5; ++dx) {
            int yy = y + dy - 2, xx = x + dx - 2;
            bool in = (yy >= 0) && (yy < Hn) && (xx >= 0) && (xx < Wn);
            a[dy][dx] = in ? PaCur[idx + (dy - 2) * Wn + (dx - 2)] : -1e30f;
        }
    }

    float s[3][3];
    float aliveC = 0.f;
#pragma unroll
    for (int qy = 0; qy < 3; ++qy) {
#pragma unroll
        for (int qx = 0; qx < 3; ++qx) {
            float pm = a[qy][qx];
            pm = fmaxf(pm, a[qy][qx + 1]);
            pm = fmaxf(pm, a[qy][qx + 2]);
            pm = fmaxf(pm, a[qy + 1][qx]);
            pm = fmaxf(pm, a[qy + 1][qx + 1]);
            pm = fmaxf(pm, a[qy + 1][qx + 2]);
            pm = fmaxf(pm, a[qy + 2][qx]);
            pm = fmaxf(pm, a[qy + 2][qx + 1]);
            pm = fmaxf(pm, a[qy + 2][qx + 2]);
            float alive = (pm >= ALPHA_T) ? 1.f : 0.f;
            if (qy == 1 && qx == 1) aliveC = alive;
            int yy = y + qy - 1, xx = x + qx - 1;
            bool in = (yy >= 0) && (yy < Hn) && (xx >= 0) && (xx < Wn);
            s[qy][qx] = in ? a[qy + 1][qx + 1] * alive : -1e30f;
        }
    }

    float ps = s[0][0];
    ps = fmaxf(ps, s[0][1]); ps = fmaxf(ps, s[0][2]);
    ps = fmaxf(ps, s[1][0]); ps = fmaxf(ps, s[1][1]); ps = fmaxf(ps, s[1][2]);
    ps = fmaxf(ps, s[2][0]); ps = fmaxf(ps, s[2][1]); ps = fmaxf(ps, s[2][2]);
    float amN = (ps >= ALPHA_T) ? 1.f : 0.f;

    bool fm = maskT[idx] != 0;
#pragma unroll
    for (int cg = 0; cg < 4; ++cg) {
        float4 pv = *(const float4*)&P[idx * Cn + cg * 4];
        float4 sv = *(const float4*)&S[idx * Cn + cg * 4];
        float4 v;
        v.x = (fm ? pv.x : sv.x) * aliveC;
        v.y = (fm ? pv.y : sv.y) * aliveC;
        v.z = (fm ? pv.z : sv.z) * aliveC;
        v.w = (fm ? pv.w : sv.w) * aliveC;
        *(float4*)&Snext[idx * Cn + cg * 4] = v;
        if (cg == 0) PaNxt[idx] = v.w;            // alpha(S_next) prefill
    }
    amNext[idx] = amN;
}

// ---------------------------------------------------------------------------
// init_plane: amF = alive(S0), PaM = alpha(S0)
// ---------------------------------------------------------------------------
__global__ __launch_bounds__(256) void init_plane(
    const float* __restrict__ S0, float* __restrict__ amF, float* __restrict__ Pa0)
{
    int idx = blockIdx.x * 256 + threadIdx.x;
    int x  = idx % Wn;
    int t1 = idx / Wn;
    int y  = t1 % Hn;
    float pooled = -1e30f;
#pragma unroll
    for (int dy = -1; dy <= 1; ++dy) {
#pragma unroll
        for (int dx = -1; dx <= 1; ++dx) {
            int yy = y + dy, xx = x + dx;
            bool in = (yy >= 0) && (yy < Hn) && (xx >= 0) && (xx < Wn);
            if (in) pooled = fmaxf(pooled, S0[(idx + dy * Wn + dx) * Cn + 3]);
        }
    }
    amF[idx] = (pooled >= ALPHA_T) ? 1.f : 0.f;
    Pa0[idx] = S0[idx * Cn + 3];
}

// ---------------------------------------------------------------------------
// transpose_w2: W2[16][128] -> W2T[128][16]
// ---------------------------------------------------------------------------
__global__ __launch_bounds__(256) void transpose_w2(
    const float* __restrict__ W2, float* __restrict__ W2T)
{
    int i = blockIdx.x * 256 + threadIdx.x;
    if (i < Cn * HID) {
        int c = i >> 7;
        int j = i & 127;
        W2T[j * Cn + c] = W2[i];
    }
}

// ---------------------------------------------------------------------------
// Init copy: stacked[0] = initial_state
// ---------------------------------------------------------------------------
__global__ __launch_bounds__(256) void copy_init(
    const float4* __restrict__ src, float4* __restrict__ dst, int n4)
{
    int i = blockIdx.x * 256 + threadIdx.x;
    if (i < n4) dst[i] = src[i];
}

// ---------------------------------------------------------------------------
// RGB: rgb = trunc(clip(1 - clip(a,0,1) + rgb_ch, 0, 1) * 255), stored as f32
// ---------------------------------------------------------------------------
__global__ __launch_bounds__(256) void rgb_kernel(
    const float* __restrict__ stacked, float* __restrict__ rgb, int npix)
{
    int idx = blockIdx.x * 256 + threadIdx.x;
    if (idx >= npix) return;
    float4 s = *(const float4*)&stacked[idx * Cn];
    float a = fminf(fmaxf(s.w, 0.f), 1.f);
    float base = 1.f - a;
    rgb[idx * 3 + 0] = truncf(fminf(fmaxf(base + s.x, 0.f), 1.f) * 255.f);
    rgb[idx * 3 + 1] = truncf(fminf(fmaxf(base + s.y, 0.f), 1.f) * 255.f);
    rgb[idx * 3 + 2] = truncf(fminf(fmaxf(base + s.z, 0.f), 1.f) * 255.f);
}

extern "C" void kernel_launch(void* const* d_in, const int* in_sizes, int n_in,
                              void* d_out, int out_size, void* d_ws, size_t ws_size,
                              hipStream_t stream) {
    const float* init = (const float*)d_in[0];
    const float* W1   = (const float*)d_in[1];
    const float* b1   = (const float*)d_in[2];
    const float* W2   = (const float*)d_in[3];
    const int*   upd  = (const int*)d_in[4];

    float* out     = (float*)d_out;
    float* rgb     = out;                 // [NFRAME*PIX*3]
    float* stacked = out + RGB_TOTAL;     // [NFRAME*PIX*16]
    // Transient buffers staged in the rgb region (written last by rgb_kernel):
    //   P    : PIX*16 floats        (3.28M)
    //   Pa0/1: PIX floats each      (0.41M)
    //   amF  : PIX floats           (0.20M)
    //   W2T  : 2048 floats
    //   list : Sn*PIX ints          (6.55M)
    //   counts/base/nAct : ints     (~51K)
    // Total ~10.5M floats-equivalent <= RGB_TOTAL (20.3M). OK.
    float* P    = out;
    float* Pa0  = out + (size_t)PIX * Cn;
    float* Pa1  = Pa0 + PIX;
    float* amF  = Pa1 + PIX;
    float* W2T  = amF + PIX;
    int*   list   = (int*)(W2T + 2048);
    int*   counts = list + (size_t)Sn * PIX;
    int*   base   = counts + Sn * NCHUNK;
    int*   nAct   = base + Sn * NCHUNK;

    const int blocks_pix = PIX / 256;     // 800, exact

    copy_init<<<(PIX * Cn / 4 + 255) / 256, 256, 0, stream>>>(
        (const float4*)init, (float4*)stacked, PIX * Cn / 4);
    init_plane<<<blocks_pix, 256, 0, stream>>>(stacked, amF, Pa0);
    transpose_w2<<<(Cn * HID + 255) / 256, 256, 0, stream>>>(W2, W2T);

    // Build all 32 active-pixel lists once (upd_mask is a static input).
    mask_count<<<Sn * NCHUNK, 256, 0, stream>>>(upd, counts);
    scan_counts<<<Sn, 1024, 0, stream>>>(counts, base, nAct);
    mask_fill<<<Sn * NCHUNK, 256, 0, stream>>>(upd, base, list);

    float* PaCur = Pa0;
    float* PaNxt = Pa1;
    for (int t = 0; t < Sn; ++t) {
        step_update_c<<<PIX / 128, 256, 0, stream>>>(
            stacked + (size_t)t * STACK_FRAME, amF, nAct + t, list + (size_t)t * PIX,
            P, PaCur, W1, b1, W2T);
        step_mask<<<blocks_pix, 256, 0, stream>>>(
            P, PaCur, stacked + (size_t)t * STACK_FRAME, upd + (size_t)t * PIX,
            stacked + (size_t)(t + 1) * STACK_FRAME, amF, PaNxt);
        float* tmp = PaCur; PaCur = PaNxt; PaNxt = tmp;
    }

    const int npix_all = NFRAME * PIX;
    rgb_kernel<<<(npix_all + 255) / 256, 256, 0, stream>>>(stacked, rgb, npix_all);
}

// Round 4
// 5125.147 us; speedup vs baseline: 1.0625x; 1.0625x over previous
//
#include <hip/hip_runtime.h>

#define Cn 16
#define Bn 128
#define Hn 40
#define Wn 40
#define Sn 32
#define HID 128
#define PIX (Bn * Hn * Wn)          // 204800
#define NFRAME (Sn + 1)             // 33
#define RGB_TOTAL (NFRAME * PIX * 3)
#define STACK_FRAME (PIX * Cn)
#define ALPHA_T 0.1f

// ---------------------------------------------------------------------------
// Perception for one pixel: perc[48] = [masked(16) | sobel_x(16) | sobel_y(16)]
// Fully unrolled -> perc stays in registers.
// ---------------------------------------------------------------------------
__device__ __forceinline__ void perception(
    const float* __restrict__ S, const float* __restrict__ amF,
    int idx, int x, int y, float* perc)
{
    float am[3][3];
#pragma unroll
    for (int dy = 0; dy < 3; ++dy) {
#pragma unroll
        for (int dx = 0; dx < 3; ++dx) {
            int yy = y + dy - 1, xx = x + dx - 1;
            bool in = (yy >= 0) && (yy < Hn) && (xx >= 0) && (xx < Wn);
            am[dy][dx] = in ? amF[idx + (dy - 1) * Wn + (dx - 1)] : 0.f;
        }
    }

#pragma unroll
    for (int cg = 0; cg < 4; ++cg) {
        float4 m[3][3];
#pragma unroll
        for (int dy = 0; dy < 3; ++dy) {
#pragma unroll
            for (int dx = 0; dx < 3; ++dx) {
                int yy = y + dy - 1, xx = x + dx - 1;
                bool in = (yy >= 0) && (yy < Hn) && (xx >= 0) && (xx < Wn);
                float4 v;
                if (in) {
                    v = *(const float4*)&S[(idx + (dy - 1) * Wn + (dx - 1)) * Cn + cg * 4];
                    float a = am[dy][dx];
                    v.x *= a; v.y *= a; v.z *= a; v.w *= a;
                } else {
                    v.x = 0.f; v.y = 0.f; v.z = 0.f; v.w = 0.f;
                }
                m[dy][dx] = v;
            }
        }
        perc[cg * 4 + 0] = m[1][1].x;
        perc[cg * 4 + 1] = m[1][1].y;
        perc[cg * 4 + 2] = m[1][1].z;
        perc[cg * 4 + 3] = m[1][1].w;
        perc[16 + cg * 4 + 0] = ((m[0][2].x - m[0][0].x) + 2.f * (m[1][2].x - m[1][0].x) + (m[2][2].x - m[2][0].x)) * 0.125f;
        perc[16 + cg * 4 + 1] = ((m[0][2].y - m[0][0].y) + 2.f * (m[1][2].y - m[1][0].y) + (m[2][2].y - m[2][0].y)) * 0.125f;
        perc[16 + cg * 4 + 2] = ((m[0][2].z - m[0][0].z) + 2.f * (m[1][2].z - m[1][0].z) + (m[2][2].z - m[2][0].z)) * 0.125f;
        perc[16 + cg * 4 + 3] = ((m[0][2].w - m[0][0].w) + 2.f * (m[1][2].w - m[1][0].w) + (m[2][2].w - m[2][0].w)) * 0.125f;
        perc[32 + cg * 4 + 0] = ((m[2][0].x - m[0][0].x) + 2.f * (m[2][1].x - m[0][1].x) + (m[2][2].x - m[0][2].x)) * 0.125f;
        perc[32 + cg * 4 + 1] = ((m[2][0].y - m[0][0].y) + 2.f * (m[2][1].y - m[0][1].y) + (m[2][2].y - m[0][2].y)) * 0.125f;
        perc[32 + cg * 4 + 2] = ((m[2][0].z - m[0][0].z) + 2.f * (m[2][1].z - m[0][1].z) + (m[2][2].z - m[0][2].z)) * 0.125f;
        perc[32 + cg * 4 + 3] = ((m[2][0].w - m[0][0].w) + 2.f * (m[2][1].w - m[0][1].w) + (m[2][2].w - m[0][2].w)) * 0.125f;
    }
}

// ---------------------------------------------------------------------------
// Kernel A (dense, 2 pixels per thread): P = S + upd_mask * MLP(perception)
// Weights read wave-uniform (scalar pipe) from the packed layout
//   Wp[j][64] = [ W1 row j (48) | W2T row j (16) ]
// so each j-iteration is 4 aligned s_load_dwordx16 from one base, amortized
// over 128 FMAs (2 pixels). No LDS (R1 lesson: DS pipe oversubscribes).
// ---------------------------------------------------------------------------
__global__ __launch_bounds__(128) void step_update(
    const float* __restrict__ S,      // [PIX*16] current (masked) state
    const float* __restrict__ amF,    // [PIX] alive mask of S
    const int*   __restrict__ maskT,  // [PIX] update mask for this step
    float*       __restrict__ P,      // [PIX*16] out: pre-mask new state
    float*       __restrict__ Pa,     // [PIX] out: alpha plane of P
    const float* __restrict__ Wp,     // [128*64] packed weights
    const float* __restrict__ b1)     // [128]
{
    int idxA = blockIdx.x * 256 + threadIdx.x;   // lanes consecutive
    int idxB = idxA + 128;

    int xA = idxA % Wn, tA = idxA / Wn, yA = tA % Hn;
    int xB = idxB % Wn, tB = idxB / Wn, yB = tB % Hn;

    float percA[48], percB[48];
    perception(S, amF, idxA, xA, yA, percA);
    perception(S, amF, idxB, xB, yB, percB);

    float updA[16], updB[16];
#pragma unroll
    for (int c = 0; c < 16; ++c) { updA[c] = 0.f; updB[c] = 0.f; }

    for (int j = 0; j < HID; ++j) {
        const float* w = &Wp[j * 64];
        float bj = b1[j];
        float a0 = bj, a1 = 0.f, a2 = 0.f, a3 = 0.f;
        float c0 = bj, c1 = 0.f, c2 = 0.f, c3 = 0.f;
#pragma unroll
        for (int q = 0; q < 12; ++q) {
            float w0 = w[q], w1 = w[12 + q], w2 = w[24 + q], w3 = w[36 + q];
            a0 = fmaf(percA[q],      w0, a0);  c0 = fmaf(percB[q],      w0, c0);
            a1 = fmaf(percA[12 + q], w1, a1);  c1 = fmaf(percB[12 + q], w1, c1);
            a2 = fmaf(percA[24 + q], w2, a2);  c2 = fmaf(percB[24 + q], w2, c2);
            a3 = fmaf(percA[36 + q], w3, a3);  c3 = fmaf(percB[36 + q], w3, c3);
        }
        float hA = fmaxf((a0 + a1) + (a2 + a3), 0.f);
        float hB = fmaxf((c0 + c1) + (c2 + c3), 0.f);
#pragma unroll
        for (int c = 0; c < 16; ++c) {
            float wv = w[48 + c];
            updA[c] = fmaf(hA, wv, updA[c]);
            updB[c] = fmaf(hB, wv, updB[c]);
        }
    }

    float fmA = (float)maskT[idxA];
    float fmB = (float)maskT[idxB];

#pragma unroll
    for (int cg = 0; cg < 4; ++cg) {
        float4 s = *(const float4*)&S[idxA * Cn + cg * 4];
        float4 o;
        o.x = s.x + updA[cg * 4 + 0] * fmA;
        o.y = s.y + updA[cg * 4 + 1] * fmA;
        o.z = s.z + updA[cg * 4 + 2] * fmA;
        o.w = s.w + updA[cg * 4 + 3] * fmA;
        *(float4*)&P[idxA * Cn + cg * 4] = o;
        if (cg == 0) Pa[idxA] = o.w;             // channel 3 = alpha
    }
#pragma unroll
    for (int cg = 0; cg < 4; ++cg) {
        float4 s = *(const float4*)&S[idxB * Cn + cg * 4];
        float4 o;
        o.x = s.x + updB[cg * 4 + 0] * fmB;
        o.y = s.y + updB[cg * 4 + 1] * fmB;
        o.z = s.z + updB[cg * 4 + 2] * fmB;
        o.w = s.w + updB[cg * 4 + 3] * fmB;
        *(float4*)&P[idxB * Cn + cg * 4] = o;
        if (cg == 0) Pa[idxB] = o.w;
    }
}

// ---------------------------------------------------------------------------
// Kernel B: S_next = P * alive(P); amNext = alive(S_next) for next step's A.
// Alpha gathered from the compact plane Pa (coalesced 4B-stride).
// ---------------------------------------------------------------------------
__global__ __launch_bounds__(256) void step_mask(
    const float* __restrict__ P,
    const float* __restrict__ Pa,
    float*       __restrict__ Snext,
    float*       __restrict__ amNext)
{
    int idx = blockIdx.x * 256 + threadIdx.x;
    int x  = idx % Wn;
    int t1 = idx / Wn;
    int y  = t1 % Hn;

    float a[5][5];
#pragma unroll
    for (int dy = 0; dy < 5; ++dy) {
#pragma unroll
        for (int dx = 0; dx < 5; ++dx) {
            int yy = y + dy - 2, xx = x + dx - 2;
            bool in = (yy >= 0) && (yy < Hn) && (xx >= 0) && (xx < Wn);
            a[dy][dx] = in ? Pa[idx + (dy - 2) * Wn + (dx - 2)] : -1e30f;
        }
    }

    float s[3][3];
    float aliveC = 0.f;
#pragma unroll
    for (int qy = 0; qy < 3; ++qy) {
#pragma unroll
        for (int qx = 0; qx < 3; ++qx) {
            float p = a[qy][qx];
            p = fmaxf(p, a[qy][qx + 1]);
            p = fmaxf(p, a[qy][qx + 2]);
            p = fmaxf(p, a[qy + 1][qx]);
            p = fmaxf(p, a[qy + 1][qx + 1]);
            p = fmaxf(p, a[qy + 1][qx + 2]);
            p = fmaxf(p, a[qy + 2][qx]);
            p = fmaxf(p, a[qy + 2][qx + 1]);
            p = fmaxf(p, a[qy + 2][qx + 2]);
            float alive = (p >= ALPHA_T) ? 1.f : 0.f;
            if (qy == 1 && qx == 1) aliveC = alive;
            int yy = y + qy - 1, xx = x + qx - 1;
            bool in = (yy >= 0) && (yy < Hn) && (xx >= 0) && (xx < Wn);
            // masked alpha of S_next at neighbor q; OOB pads with -inf
            s[qy][qx] = in ? a[qy + 1][qx + 1] * alive : -1e30f;
        }
    }

    float ps = s[0][0];
    ps = fmaxf(ps, s[0][1]); ps = fmaxf(ps, s[0][2]);
    ps = fmaxf(ps, s[1][0]); ps = fmaxf(ps, s[1][1]); ps = fmaxf(ps, s[1][2]);
    ps = fmaxf(ps, s[2][0]); ps = fmaxf(ps, s[2][1]); ps = fmaxf(ps, s[2][2]);
    float amN = (ps >= ALPHA_T) ? 1.f : 0.f;

#pragma unroll
    for (int cg = 0; cg < 4; ++cg) {
        float4 v = *(const float4*)&P[idx * Cn + cg * 4];
        v.x *= aliveC; v.y *= aliveC; v.z *= aliveC; v.w *= aliveC;
        *(float4*)&Snext[idx * Cn + cg * 4] = v;
    }
    amNext[idx] = amN;
}

// ---------------------------------------------------------------------------
// init_am: alive mask of the initial state (3x3 pooled alpha >= T)
// ---------------------------------------------------------------------------
__global__ __launch_bounds__(256) void init_am(
    const float* __restrict__ S0, float* __restrict__ amF)
{
    int idx = blockIdx.x * 256 + threadIdx.x;
    int x  = idx % Wn;
    int t1 = idx / Wn;
    int y  = t1 % Hn;
    float pooled = -1e30f;
#pragma unroll
    for (int dy = -1; dy <= 1; ++dy) {
#pragma unroll
        for (int dx = -1; dx <= 1; ++dx) {
            int yy = y + dy, xx = x + dx;
            bool in = (yy >= 0) && (yy < Hn) && (xx >= 0) && (xx < Wn);
            if (in) pooled = fmaxf(pooled, S0[(idx + dy * Wn + dx) * Cn + 3]);
        }
    }
    amF[idx] = (pooled >= ALPHA_T) ? 1.f : 0.f;
}

// ---------------------------------------------------------------------------
// pack_weights: Wp[j][64] = [W1 row j (48) | W2 column j (16)]
// ---------------------------------------------------------------------------
__global__ __launch_bounds__(256) void pack_weights(
    const float* __restrict__ W1, const float* __restrict__ W2,
    float* __restrict__ Wp)
{
    int i = blockIdx.x * 256 + threadIdx.x;
    if (i < HID * 64) {
        int j = i >> 6;
        int k = i & 63;
        Wp[i] = (k < 48) ? W1[j * 48 + k] : W2[(k - 48) * HID + j];
    }
}

// ---------------------------------------------------------------------------
// Init copy: stacked[0] = initial_state
// ---------------------------------------------------------------------------
__global__ __launch_bounds__(256) void copy_init(
    const float4* __restrict__ src, float4* __restrict__ dst, int n4)
{
    int i = blockIdx.x * 256 + threadIdx.x;
    if (i < n4) dst[i] = src[i];
}

// ---------------------------------------------------------------------------
// RGB: rgb = trunc(clip(1 - clip(a,0,1) + rgb_ch, 0, 1) * 255), stored as f32
// ---------------------------------------------------------------------------
__global__ __launch_bounds__(256) void rgb_kernel(
    const float* __restrict__ stacked, float* __restrict__ rgb, int npix)
{
    int idx = blockIdx.x * 256 + threadIdx.x;
    if (idx >= npix) return;
    float4 s = *(const float4*)&stacked[idx * Cn];
    float a = fminf(fmaxf(s.w, 0.f), 1.f);
    float base = 1.f - a;
    rgb[idx * 3 + 0] = truncf(fminf(fmaxf(base + s.x, 0.f), 1.f) * 255.f);
    rgb[idx * 3 + 1] = truncf(fminf(fmaxf(base + s.y, 0.f), 1.f) * 255.f);
    rgb[idx * 3 + 2] = truncf(fminf(fmaxf(base + s.z, 0.f), 1.f) * 255.f);
}

extern "C" void kernel_launch(void* const* d_in, const int* in_sizes, int n_in,
                              void* d_out, int out_size, void* d_ws, size_t ws_size,
                              hipStream_t stream) {
    const float* init = (const float*)d_in[0];
    const float* W1   = (const float*)d_in[1];
    const float* b1   = (const float*)d_in[2];
    const float* W2   = (const float*)d_in[3];
    const int*   upd  = (const int*)d_in[4];

    float* out     = (float*)d_out;
    float* rgb     = out;                 // [NFRAME*PIX*3]
    float* stacked = out + RGB_TOTAL;     // [NFRAME*PIX*16]
    // Transient buffers staged in the rgb region (written last by rgb_kernel):
    //   P   : PIX*16 floats
    //   Pa  : PIX floats (alpha plane of P)
    //   amF : PIX floats (alive mask field of current S)
    //   Wp  : 8192 floats (packed weights)
    // Total PIX*18 + 8K = 3.7M floats <= RGB_TOTAL (20.3M). OK.
    float* P   = out;
    float* Pa  = out + (size_t)PIX * Cn;
    float* amF = out + (size_t)PIX * (Cn + 1);
    float* Wp  = out + (size_t)PIX * (Cn + 2);

    const int blocks_pix = PIX / 256;     // 800, exact

    copy_init<<<(PIX * Cn / 4 + 255) / 256, 256, 0, stream>>>(
        (const float4*)init, (float4*)stacked, PIX * Cn / 4);
    init_am<<<blocks_pix, 256, 0, stream>>>(stacked, amF);
    pack_weights<<<(HID * 64 + 255) / 256, 256, 0, stream>>>(W1, W2, Wp);

    for (int t = 0; t < Sn; ++t) {
        step_update<<<PIX / 256, 128, 0, stream>>>(
            stacked + (size_t)t * STACK_FRAME, amF, upd + (size_t)t * PIX,
            P, Pa, Wp, b1);
        step_mask<<<blocks_pix, 256, 0, stream>>>(
            P, Pa, stacked + (size_t)(t + 1) * STACK_FRAME, amF);
    }

    const int npix_all = NFRAME * PIX;
    rgb_kernel<<<(npix_all + 255) / 256, 256, 0, stream>>>(stacked, rgb, npix_all);
}